// Round 7
// baseline (547.744 us; speedup 1.0000x reference)
//
#include <hip/hip_runtime.h>
#include <hip/hip_bf16.h>

// BS=8, N=64, H=512, L=5.  M = 32768 edge rows.
// 8 regular launches:
//   prep | nm0+em0 | edge_rank1(t=0) | edge x4 (t=1..4) | out
// edge block = one (b,i) group: 64x512x512 MFMA GEMM (es slab read ONCE),
// fused lrelu/es-store/agg/node-update + GEMV for next layer's nm.

typedef short bf16x8 __attribute__((ext_vector_type(8)));
typedef float f32x4 __attribute__((ext_vector_type(4)));

__device__ __forceinline__ float lrelu(float x) { return x > 0.f ? x : 0.01f * x; }
__device__ __forceinline__ float asf(unsigned int u) { return __uint_as_float(u); }

__device__ __forceinline__ void cp16(const void* g, void* l) {
    __builtin_amdgcn_global_load_lds(
        (const __attribute__((address_space(1))) unsigned int*)g,
        (__attribute__((address_space(3))) unsigned int*)l,
        16, 0, 0);
}

__device__ __forceinline__ void cvt4store(__hip_bfloat16* dst, float4 v) {
    __hip_bfloat16 tmp[4] = {__float2bfloat16(v.x), __float2bfloat16(v.y),
                             __float2bfloat16(v.z), __float2bfloat16(v.w)};
    *(uint2*)dst = *(const uint2*)tmp;
}

// ---------------------------------------------------------------------------
__global__ __launch_bounds__(256) void prep_kernel(
    const float* __restrict__ roi, const float* __restrict__ img,
    const float* __restrict__ nW, const float* __restrict__ eW,
    const int* __restrict__ mask,
    __hip_bfloat16* __restrict__ nWb, __hip_bfloat16* __restrict__ eWb,
    float* __restrict__ nodef, __hip_bfloat16* __restrict__ nodeb,
    float* __restrict__ edge_init, float* __restrict__ denom)
{
    int bid = blockIdx.x, tid = threadIdx.x;
    if (bid < 2560) {
        const float* src = (bid < 1280) ? nW : eW;
        __hip_bfloat16* dst = (bid < 1280) ? nWb : eWb;
        int i = ((bid < 1280) ? bid : bid - 1280) * 256 + tid;   // float4 idx
        cvt4store(dst + (size_t)i * 4, ((const float4*)src)[i]);
    } else if (bid < 2816) {
        int i = (bid - 2560) * 256 + tid;
        float4 v = ((const float4*)roi)[i];
        ((float4*)nodef)[i] = v;
        cvt4store(nodeb + (size_t)i * 4, v);
    } else if (bid < 3840) {
        int pid = (bid - 2816) * 4 + (tid >> 6);   // (b*512+h)
        int l = tid & 63;
        const float* p = img + (size_t)pid * 196;
        float s = 0.f;
        for (int x = l; x < 196; x += 64) s += p[x];
#pragma unroll
        for (int o = 1; o < 64; o <<= 1) s += __shfl_xor(s, o, 64);
        if (l == 0) edge_init[pid] = s * (1.f / 196.f);
    } else {
        int pid = (bid - 3840) * 256 + tid;
        if (pid < 512) {
            const int* m = mask + pid * 64;
            int s = 0;
#pragma unroll
            for (int j = 0; j < 64; ++j) s += m[j];
            denom[pid] = (float)s + 1.f;
        }
    }
}

// ---------------------------------------------------------------------------
// blocks 0..63: nm(0) GEMM; blocks 64..191: em0 dots
__global__ __launch_bounds__(256) void nm0em0_kernel(
    const __hip_bfloat16* __restrict__ A,    // nodeb 512x512
    const __hip_bfloat16* __restrict__ W0,   // nWb layer 0
    const float* __restrict__ nB,
    const float* __restrict__ edge_init, const float* __restrict__ eW,
    const float* __restrict__ eB,
    float* __restrict__ nm, float* __restrict__ em0)
{
    __shared__ __align__(16) __hip_bfloat16 sA[64 * 32];
    __shared__ __align__(16) __hip_bfloat16 sB[64 * 32];
    int blk = blockIdx.x, tid = threadIdx.x;
    int w = tid >> 6, l = tid & 63, lq = l >> 4, lr = l & 15;

    if (blk < 64) {
        int bm = blk >> 3, bn = blk & 7;
        const char* aB = (const char*)A + (size_t)bm * 65536;
        const char* bB = (const char*)W0 + (size_t)bn * 65536;
        int offG = (tid >> 2) * 1024 + (tid & 3) * 16;
        f32x4 acc[4] = {};
        for (int kt = 0; kt < 16; ++kt) {
            cp16(aB + offG + kt * 64, (char*)sA + tid * 16);
            cp16(bB + offG + kt * 64, (char*)sB + tid * 16);
            __syncthreads();
            bf16x8 af = *(const bf16x8*)&sA[(w * 16 + lr) * 32 + lq * 8];
#pragma unroll
            for (int ni = 0; ni < 4; ++ni) {
                bf16x8 bv = *(const bf16x8*)&sB[(ni * 16 + lr) * 32 + lq * 8];
                acc[ni] = __builtin_amdgcn_mfma_f32_16x16x32_bf16(af, bv, acc[ni], 0, 0, 0);
            }
            __syncthreads();
        }
#pragma unroll
        for (int ni = 0; ni < 4; ++ni) {
            int col = bn * 64 + ni * 16 + lr;
            float bv = nB[col];
#pragma unroll
            for (int r = 0; r < 4; ++r) {
                int row = bm * 64 + w * 16 + lq * 4 + r;
                nm[(size_t)row * 512 + col] = acc[ni][r] + bv;
            }
        }
    } else {
        int wid = (blk - 64) * 4 + w;   // 0..511, 8 dots each
#pragma unroll
        for (int k = 0; k < 8; ++k) {
            int d = wid * 8 + k;
            int b = d >> 9, o = d & 511;
            const float4* ei = (const float4*)(edge_init + b * 512);
            const float4* wv = (const float4*)(eW + (size_t)o * 512);
            float4 a0 = ei[l * 2], a1 = ei[l * 2 + 1];
            float4 b0 = wv[l * 2], b1 = wv[l * 2 + 1];
            float s = a0.x * b0.x + a0.y * b0.y + a0.z * b0.z + a0.w * b0.w
                    + a1.x * b1.x + a1.y * b1.y + a1.z * b1.z + a1.w * b1.w;
#pragma unroll
            for (int o2 = 1; o2 < 64; o2 <<= 1) s += __shfl_xor(s, o2, 64);
            if (l == 0) em0[d] = s + eB[o];
        }
    }
}

// ---------------------------------------------------------------------------
__device__ __forceinline__ void gemv_next(
    const float* snode, const __hip_bfloat16* __restrict__ Wn,
    const float* __restrict__ bn, float* __restrict__ nm_out, int g, int tid)
{
    const float4* nr4 = (const float4*)snode;
#pragma unroll
    for (int oo = 0; oo < 2; ++oo) {
        int o = tid + oo * 256;
        const bf16x8* wr = (const bf16x8*)(Wn + (size_t)o * 512);
        float s = 0.f;
#pragma unroll 8
        for (int k = 0; k < 64; ++k) {
            union { bf16x8 v; uint4 u; } W; W.v = wr[k];
            float4 n0 = nr4[2 * k], n1 = nr4[2 * k + 1];
            s += asf(W.u.x << 16) * n0.x + asf(W.u.x & 0xFFFF0000u) * n0.y;
            s += asf(W.u.y << 16) * n0.z + asf(W.u.y & 0xFFFF0000u) * n0.w;
            s += asf(W.u.z << 16) * n1.x + asf(W.u.z & 0xFFFF0000u) * n1.y;
            s += asf(W.u.w << 16) * n1.z + asf(W.u.w & 0xFFFF0000u) * n1.w;
        }
        nm_out[(size_t)g * 512 + o] = s + bn[o];
    }
}

// ---------------------------------------------------------------------------
__global__ __launch_bounds__(256) void edge_rank1(
    const float* __restrict__ nm, const float* __restrict__ em0,
    const int* __restrict__ mask,
    __hip_bfloat16* __restrict__ es_dst,
    const float* __restrict__ denom, float* __restrict__ nodef,
    const __hip_bfloat16* __restrict__ Wn, const float* __restrict__ bn,
    float* __restrict__ nm_out)
{
    __shared__ float snode[512];
    int g = blockIdx.x, tid = threadIdx.x, b = g >> 6;
    const float* nmb = nm + (size_t)b * 32768;
    const int* mrow = mask + g * 64;
    float dv = denom[g];
#pragma unroll
    for (int cc = tid; cc < 512; cc += 256) {
        float nmi = nm[(size_t)g * 512 + cc];
        float emb = em0[b * 512 + cc];
        __hip_bfloat16* erow = es_dst + (size_t)(g * 64) * 512 + cc;
        float aggv = 0.f;
#pragma unroll 4
        for (int j = 0; j < 64; ++j) {
            float nmj = nmb[j * 512 + cc];
            float es = lrelu(nmi + nmj + emb);
            erow[(size_t)j * 512] = __float2bfloat16(es);
            aggv += es * nmj * (float)mrow[j];
        }
        float nf = (nmi + aggv) / dv;
        size_t idx = (size_t)g * 512 + cc;
        float ns = nodef[idx] + lrelu(nf);
        nodef[idx] = ns;
        snode[cc] = ns;
    }
    __syncthreads();
    gemv_next(snode, Wn, bn, nm_out, g, tid);
}

// ---------------------------------------------------------------------------
__global__ void __launch_bounds__(256, 2) edge_kernel(
    const __hip_bfloat16* __restrict__ es_src,
    const __hip_bfloat16* __restrict__ eWt,
    const float* __restrict__ eBt,
    const float* __restrict__ nm_in,
    const int* __restrict__ mask,
    __hip_bfloat16* __restrict__ es_dst,
    const float* __restrict__ denom, float* __restrict__ nodef,
    const __hip_bfloat16* __restrict__ Wn, const float* __restrict__ bn,
    float* __restrict__ nm_out,
    int write_es, int do_gemv)
{
    __shared__ __align__(16) __hip_bfloat16 sh[18432];  // sA 4KB | sB 32KB
    __hip_bfloat16* sA = sh;
    __hip_bfloat16* sB = sh + 2048;

    int g = blockIdx.x, tid = threadIdx.x;
    int w = tid >> 6, l = tid & 63, lq = l >> 4, lr = l & 15;
    int b = g >> 6;

    const char* aB = (const char*)es_src + (size_t)g * 65536;  // 64 rows x 1024B
    const char* bB = (const char*)eWt;
    int aOff = (tid >> 2) * 1024 + (tid & 3) * 16;

    f32x4 acc[4][8] = {};
    for (int kt = 0; kt < 16; ++kt) {
        int ko = kt * 64;
        cp16(aB + aOff + ko, (char*)sA + tid * 16);
#pragma unroll
        for (int i = 0; i < 8; ++i)
            cp16(bB + aOff + i * 65536 + ko, (char*)sB + tid * 16 + i * 4096);
        __syncthreads();
        bf16x8 af[4], bv[8];
#pragma unroll
        for (int mi = 0; mi < 4; ++mi)
            af[mi] = *(const bf16x8*)&sA[(mi * 16 + lr) * 32 + lq * 8];
#pragma unroll
        for (int ni = 0; ni < 8; ++ni)
            bv[ni] = *(const bf16x8*)&sB[(w * 128 + ni * 16 + lr) * 32 + lq * 8];
#pragma unroll
        for (int mi = 0; mi < 4; ++mi)
#pragma unroll
            for (int ni = 0; ni < 8; ++ni)
                acc[mi][ni] = __builtin_amdgcn_mfma_f32_16x16x32_bf16(af[mi], bv[ni], acc[mi][ni], 0, 0, 0);
        __syncthreads();
    }

    int cbase = w * 128;
    const float* nmb = nm_in + (size_t)b * 32768;
    const int* mrow = mask + g * 64;
    float dv = denom[g];

    float nmraw[8], nmi8[8];
#pragma unroll
    for (int ni = 0; ni < 8; ++ni) {
        int c = cbase + ni * 16 + lr;
        nmraw[ni] = nm_in[(size_t)g * 512 + c];
        nmi8[ni] = nmraw[ni] + eBt[c];
    }
    float aggv[8] = {};
#pragma unroll
    for (int mi = 0; mi < 4; ++mi) {
#pragma unroll
        for (int r = 0; r < 4; ++r) {
            int j = mi * 16 + lq * 4 + r;
            float mf = (float)mrow[j];
            const float* nrow = nmb + (size_t)j * 512;
            size_t erow = ((size_t)(g * 64 + j)) * 512;
#pragma unroll
            for (int ni = 0; ni < 8; ++ni) {
                int c = cbase + ni * 16 + lr;
                float nmj = nrow[c];
                float es = lrelu(acc[mi][ni][r] + nmi8[ni] + nmj);
                if (write_es) es_dst[erow + c] = __float2bfloat16(es);
                aggv[ni] += es * nmj * mf;
            }
        }
    }
    float* snode = (float*)sh;   // reuse LDS (all frag reads complete)
#pragma unroll
    for (int ni = 0; ni < 8; ++ni) {
        float v = aggv[ni];
        v += __shfl_xor(v, 16, 64);
        v += __shfl_xor(v, 32, 64);
        if (lq == 0) {
            int c = cbase + ni * 16 + lr;
            size_t idx = (size_t)g * 512 + c;
            float nf = (nmraw[ni] + v) / dv;
            float ns = nodef[idx] + lrelu(nf);
            nodef[idx] = ns;
            snode[c] = ns;
        }
    }
    if (do_gemv) {
        __syncthreads();
        gemv_next(snode, Wn, bn, nm_out, g, tid);
    }
}

// ---------------------------------------------------------------------------
__global__ __launch_bounds__(256) void out_kernel(
    const float* __restrict__ nodef, float* __restrict__ out)
{
    size_t ch = (size_t)blockIdx.x * 256 + threadIdx.x;  // 8,388,608 float4
    int c4 = (int)(ch & 255);
    size_t r = ch >> 8;
    int b = (int)(r >> 12);
    int i = (int)((r >> 6) & 63);
    int j = (int)(r & 63);
    int c = c4 * 4;
    const float* src = (c < 512) ? (nodef + ((size_t)(b * 64 + i)) * 512 + c)
                                 : (nodef + ((size_t)(b * 64 + j)) * 512 + (c - 512));
    ((float4*)out)[ch] = *(const float4*)src;
}

// ---------------------------------------------------------------------------
extern "C" void kernel_launch(void* const* d_in, const int* in_sizes, int n_in,
                              void* d_out, int out_size, void* d_ws, size_t ws_size,
                              hipStream_t stream) {
    const float* roi  = (const float*)d_in[0];
    const float* img  = (const float*)d_in[1];
    const float* nW   = (const float*)d_in[2];
    const float* nB   = (const float*)d_in[3];
    const float* eW   = (const float*)d_in[4];
    const float* eB   = (const float*)d_in[5];
    const int*   mask = (const int*)d_in[6];

    char* ob = (char*)d_out;
    __hip_bfloat16* es0   = (__hip_bfloat16*)(ob);                 // 33.55 MB
    __hip_bfloat16* es1   = (__hip_bfloat16*)(ob + 33554432);      // 33.55 MB
    __hip_bfloat16* eWb   = (__hip_bfloat16*)(ob + 67108864);      // 2.62 MB
    __hip_bfloat16* nWb   = (__hip_bfloat16*)(ob + 69730304);      // 2.62 MB
    __hip_bfloat16* nodeb = (__hip_bfloat16*)(ob + 72351744);      // 0.52 MB
    float*          nmA   = (float*)(ob + 72876032);               // 1.05 MB
    float*          nmB   = (float*)(ob + 73924608);               // 1.05 MB
    float*          em0   = (float*)(ob + 74973184);               // 16 KB
    float*       edge_init= (float*)(ob + 74989568);               // 16 KB

    char* ws = (char*)d_ws;  // read by out_kernel while d_out is rewritten
    float* nodef = (float*)(ws);                 // 1 MB
    float* denom = (float*)(ws + 1048576);       // 2 KB
    float* outp  = (float*)d_out;

    prep_kernel<<<3842, 256, 0, stream>>>(roi, img, nW, eW, mask,
                                          nWb, eWb, nodef, nodeb, edge_init, denom);
    nm0em0_kernel<<<192, 256, 0, stream>>>(nodeb, nWb, nB, edge_init, eW, eB,
                                           nmA, em0);
    edge_rank1<<<512, 256, 0, stream>>>(nmA, em0, mask, es0, denom, nodef,
                                        nWb + 262144, nB + 512, nmB);
    for (int t = 1; t < 5; ++t) {
        const __hip_bfloat16* src = (t & 1) ? es0 : es1;
        __hip_bfloat16* dst       = (t & 1) ? es1 : es0;
        float* nin  = (t & 1) ? nmB : nmA;
        float* nout = (t & 1) ? nmA : nmB;
        int tn = (t < 4) ? (t + 1) : t;   // keep GEMV ptrs in-range at t=4
        edge_kernel<<<512, 256, 0, stream>>>(src, eWb + (size_t)t * 262144,
                                             eB + t * 512, nin, mask, dst,
                                             denom, nodef,
                                             nWb + (size_t)tn * 262144,
                                             nB + tn * 512, nout,
                                             (t < 4) ? 1 : 0, (t < 4) ? 1 : 0);
    }
    out_kernel<<<32768, 256, 0, stream>>>(nodef, outp);
}

// Round 8
// 457.947 us; speedup vs baseline: 1.1961x; 1.1961x over previous
//
#include <hip/hip_runtime.h>
#include <hip/hip_bf16.h>

// BS=8, N=64, H=512, L=5.  M = 32768 edge rows.
// 11 regular launches:
//   prep | nm0+em0 | edge_rank1(t=0,+GEMV nm1) |
//   [edge(t) | nm_gemm(t+1)] t=1..3 | edge(4) | out
// edge block = (group g, col-half): BM=64 x BN=256 x K=512 MFMA GEMM,
// fused lrelu/es-store/agg/node-update.  1024 blocks -> 4 blocks/CU.

typedef short bf16x8 __attribute__((ext_vector_type(8)));
typedef float f32x4 __attribute__((ext_vector_type(4)));

__device__ __forceinline__ float lrelu(float x) { return x > 0.f ? x : 0.01f * x; }
__device__ __forceinline__ float asf(unsigned int u) { return __uint_as_float(u); }

__device__ __forceinline__ void cp16(const void* g, void* l) {
    __builtin_amdgcn_global_load_lds(
        (const __attribute__((address_space(1))) unsigned int*)g,
        (__attribute__((address_space(3))) unsigned int*)l,
        16, 0, 0);
}

__device__ __forceinline__ void cvt4store(__hip_bfloat16* dst, float4 v) {
    __hip_bfloat16 tmp[4] = {__float2bfloat16(v.x), __float2bfloat16(v.y),
                             __float2bfloat16(v.z), __float2bfloat16(v.w)};
    *(uint2*)dst = *(const uint2*)tmp;
}

// ---------------------------------------------------------------------------
__global__ __launch_bounds__(256) void prep_kernel(
    const float* __restrict__ roi, const float* __restrict__ img,
    const float* __restrict__ nW, const float* __restrict__ eW,
    const int* __restrict__ mask,
    __hip_bfloat16* __restrict__ nWb, __hip_bfloat16* __restrict__ eWb,
    float* __restrict__ nodef, __hip_bfloat16* __restrict__ nodeb,
    float* __restrict__ edge_init, float* __restrict__ denom)
{
    int bid = blockIdx.x, tid = threadIdx.x;
    if (bid < 2560) {
        const float* src = (bid < 1280) ? nW : eW;
        __hip_bfloat16* dst = (bid < 1280) ? nWb : eWb;
        int i = ((bid < 1280) ? bid : bid - 1280) * 256 + tid;   // float4 idx
        cvt4store(dst + (size_t)i * 4, ((const float4*)src)[i]);
    } else if (bid < 2816) {
        int i = (bid - 2560) * 256 + tid;
        float4 v = ((const float4*)roi)[i];
        ((float4*)nodef)[i] = v;
        cvt4store(nodeb + (size_t)i * 4, v);
    } else if (bid < 3840) {
        int pid = (bid - 2816) * 4 + (tid >> 6);   // (b*512+h)
        int l = tid & 63;
        const float* p = img + (size_t)pid * 196;
        float s = 0.f;
        for (int x = l; x < 196; x += 64) s += p[x];
#pragma unroll
        for (int o = 1; o < 64; o <<= 1) s += __shfl_xor(s, o, 64);
        if (l == 0) edge_init[pid] = s * (1.f / 196.f);
    } else {
        int pid = (bid - 3840) * 256 + tid;
        if (pid < 512) {
            const int* m = mask + pid * 64;
            int s = 0;
#pragma unroll
            for (int j = 0; j < 64; ++j) s += m[j];
            denom[pid] = (float)s + 1.f;
        }
    }
}

// ---------------------------------------------------------------------------
// blocks 0..63: nm(0) GEMM; blocks 64..191: em0 dots
__global__ __launch_bounds__(256) void nm0em0_kernel(
    const __hip_bfloat16* __restrict__ A,    // nodeb 512x512
    const __hip_bfloat16* __restrict__ W0,   // nWb layer 0
    const float* __restrict__ nB,
    const float* __restrict__ edge_init, const float* __restrict__ eW,
    const float* __restrict__ eB,
    float* __restrict__ nm, float* __restrict__ em0)
{
    __shared__ __align__(16) __hip_bfloat16 sA[64 * 32];
    __shared__ __align__(16) __hip_bfloat16 sB[64 * 32];
    int blk = blockIdx.x, tid = threadIdx.x;
    int w = tid >> 6, l = tid & 63, lq = l >> 4, lr = l & 15;

    if (blk < 64) {
        int bm = blk >> 3, bn = blk & 7;
        const char* aB = (const char*)A + (size_t)bm * 65536;
        const char* bB = (const char*)W0 + (size_t)bn * 65536;
        int offG = (tid >> 2) * 1024 + (tid & 3) * 16;
        f32x4 acc[4] = {};
        for (int kt = 0; kt < 16; ++kt) {
            cp16(aB + offG + kt * 64, (char*)sA + tid * 16);
            cp16(bB + offG + kt * 64, (char*)sB + tid * 16);
            __syncthreads();
            bf16x8 af = *(const bf16x8*)&sA[(w * 16 + lr) * 32 + lq * 8];
#pragma unroll
            for (int ni = 0; ni < 4; ++ni) {
                bf16x8 bv = *(const bf16x8*)&sB[(ni * 16 + lr) * 32 + lq * 8];
                acc[ni] = __builtin_amdgcn_mfma_f32_16x16x32_bf16(af, bv, acc[ni], 0, 0, 0);
            }
            __syncthreads();
        }
#pragma unroll
        for (int ni = 0; ni < 4; ++ni) {
            int col = bn * 64 + ni * 16 + lr;
            float bv = nB[col];
#pragma unroll
            for (int r = 0; r < 4; ++r) {
                int row = bm * 64 + w * 16 + lq * 4 + r;
                nm[(size_t)row * 512 + col] = acc[ni][r] + bv;
            }
        }
    } else {
        int wid = (blk - 64) * 4 + w;   // 0..511, 8 dots each
#pragma unroll
        for (int k = 0; k < 8; ++k) {
            int d = wid * 8 + k;
            int b = d >> 9, o = d & 511;
            const float4* ei = (const float4*)(edge_init + b * 512);
            const float4* wv = (const float4*)(eW + (size_t)o * 512);
            float4 a0 = ei[l * 2], a1 = ei[l * 2 + 1];
            float4 b0 = wv[l * 2], b1 = wv[l * 2 + 1];
            float s = a0.x * b0.x + a0.y * b0.y + a0.z * b0.z + a0.w * b0.w
                    + a1.x * b1.x + a1.y * b1.y + a1.z * b1.z + a1.w * b1.w;
#pragma unroll
            for (int o2 = 1; o2 < 64; o2 <<= 1) s += __shfl_xor(s, o2, 64);
            if (l == 0) em0[d] = s + eB[o];
        }
    }
}

// ---------------------------------------------------------------------------
// nm GEMM for layers 2..4: nm[r][o] = nodeb[r] . W[o] + bias[o]
__global__ __launch_bounds__(256) void nm_gemm(
    const __hip_bfloat16* __restrict__ A,   // nodeb 512x512
    const __hip_bfloat16* __restrict__ W,   // nWb layer t
    const float* __restrict__ bias,
    float* __restrict__ nm)
{
    __shared__ __align__(16) __hip_bfloat16 sA[64 * 32];
    __shared__ __align__(16) __hip_bfloat16 sB[64 * 32];
    int tid = threadIdx.x;
    int bm = blockIdx.x, bn = blockIdx.y;
    int w = tid >> 6, l = tid & 63, lq = l >> 4, lr = l & 15;

    const char* aB = (const char*)A + (size_t)bm * 65536;
    const char* bB = (const char*)W + (size_t)bn * 65536;
    int offG = (tid >> 2) * 1024 + (tid & 3) * 16;

    f32x4 acc[4] = {};
    for (int kt = 0; kt < 16; ++kt) {
        cp16(aB + offG + kt * 64, (char*)sA + tid * 16);
        cp16(bB + offG + kt * 64, (char*)sB + tid * 16);
        __syncthreads();
        bf16x8 af = *(const bf16x8*)&sA[(w * 16 + lr) * 32 + lq * 8];
#pragma unroll
        for (int ni = 0; ni < 4; ++ni) {
            bf16x8 bv = *(const bf16x8*)&sB[(ni * 16 + lr) * 32 + lq * 8];
            acc[ni] = __builtin_amdgcn_mfma_f32_16x16x32_bf16(af, bv, acc[ni], 0, 0, 0);
        }
        __syncthreads();
    }
#pragma unroll
    for (int ni = 0; ni < 4; ++ni) {
        int col = bn * 64 + ni * 16 + lr;
        float bv = bias[col];
#pragma unroll
        for (int r = 0; r < 4; ++r) {
            int row = bm * 64 + w * 16 + lq * 4 + r;
            nm[(size_t)row * 512 + col] = acc[ni][r] + bv;
        }
    }
}

// ---------------------------------------------------------------------------
// GEMV (only fused into rank1, which owns a full node row in LDS)
__device__ __forceinline__ void gemv_next(
    const float* snode, const __hip_bfloat16* __restrict__ Wn,
    const float* __restrict__ bn, float* __restrict__ nm_out, int g, int tid)
{
    const float4* nr4 = (const float4*)snode;
#pragma unroll
    for (int oo = 0; oo < 2; ++oo) {
        int o = tid + oo * 256;
        const bf16x8* wr = (const bf16x8*)(Wn + (size_t)o * 512);
        float s = 0.f;
#pragma unroll 8
        for (int k = 0; k < 64; ++k) {
            union { bf16x8 v; uint4 u; } W; W.v = wr[k];
            float4 n0 = nr4[2 * k], n1 = nr4[2 * k + 1];
            s += asf(W.u.x << 16) * n0.x + asf(W.u.x & 0xFFFF0000u) * n0.y;
            s += asf(W.u.y << 16) * n0.z + asf(W.u.y & 0xFFFF0000u) * n0.w;
            s += asf(W.u.z << 16) * n1.x + asf(W.u.z & 0xFFFF0000u) * n1.y;
            s += asf(W.u.w << 16) * n1.z + asf(W.u.w & 0xFFFF0000u) * n1.w;
        }
        nm_out[(size_t)g * 512 + o] = s + bn[o];
    }
}

// ---------------------------------------------------------------------------
__global__ __launch_bounds__(256) void edge_rank1(
    const float* __restrict__ nm, const float* __restrict__ em0,
    const int* __restrict__ mask,
    __hip_bfloat16* __restrict__ es_dst,
    const float* __restrict__ denom, float* __restrict__ nodef,
    __hip_bfloat16* __restrict__ nodeb,
    const __hip_bfloat16* __restrict__ Wn, const float* __restrict__ bn,
    float* __restrict__ nm_out)
{
    __shared__ float snode[512];
    int g = blockIdx.x, tid = threadIdx.x, b = g >> 6;
    const float* nmb = nm + (size_t)b * 32768;
    const int* mrow = mask + g * 64;
    float dv = denom[g];
#pragma unroll
    for (int cc = tid; cc < 512; cc += 256) {
        float nmi = nm[(size_t)g * 512 + cc];
        float emb = em0[b * 512 + cc];
        __hip_bfloat16* erow = es_dst + (size_t)(g * 64) * 512 + cc;
        float aggv = 0.f;
#pragma unroll 4
        for (int j = 0; j < 64; ++j) {
            float nmj = nmb[j * 512 + cc];
            float es = lrelu(nmi + nmj + emb);
            erow[(size_t)j * 512] = __float2bfloat16(es);
            aggv += es * nmj * (float)mrow[j];
        }
        float nf = (nmi + aggv) / dv;
        size_t idx = (size_t)g * 512 + cc;
        float ns = nodef[idx] + lrelu(nf);
        nodef[idx] = ns;
        nodeb[idx] = __float2bfloat16(ns);
        snode[cc] = ns;
    }
    __syncthreads();
    gemv_next(snode, Wn, bn, nm_out, g, tid);
}

// ---------------------------------------------------------------------------
// t>=1: block = (g, half): C = es[g-slab] @ eWt[half]^T  (64x256x512 MFMA),
// fused lrelu/es-store/agg/node-update.  1024 blocks, 4/CU.
__global__ void __launch_bounds__(256, 4) edge_kernel(
    const __hip_bfloat16* __restrict__ es_src,
    const __hip_bfloat16* __restrict__ eWt,
    const float* __restrict__ eBt,
    const float* __restrict__ nm_in,
    const int* __restrict__ mask,
    __hip_bfloat16* __restrict__ es_dst,
    const float* __restrict__ denom, float* __restrict__ nodef,
    __hip_bfloat16* __restrict__ nodeb,
    int write_es)
{
    __shared__ __align__(16) __hip_bfloat16 sA[64 * 32];    // 4 KB
    __shared__ __align__(16) __hip_bfloat16 sB[256 * 32];   // 16 KB

    int blk = blockIdx.x, tid = threadIdx.x;
    int g = blk >> 1, half = blk & 1;
    int w = tid >> 6, l = tid & 63, lq = l >> 4, lr = l & 15;
    int b = g >> 6;

    const char* aB = (const char*)es_src + (size_t)g * 65536;       // 64 x 1024B
    const char* bB = (const char*)eWt + (size_t)half * 262144;      // 256 x 1024B
    int aOff = (tid >> 2) * 1024 + (tid & 3) * 16;

    f32x4 acc[4][4] = {};
    for (int kt = 0; kt < 16; ++kt) {
        int ko = kt * 64;
        cp16(aB + aOff + ko, (char*)sA + tid * 16);
#pragma unroll
        for (int i = 0; i < 4; ++i)
            cp16(bB + aOff + i * 65536 + ko, (char*)sB + tid * 16 + i * 4096);
        __syncthreads();
        bf16x8 af[4], bv[4];
#pragma unroll
        for (int mi = 0; mi < 4; ++mi)
            af[mi] = *(const bf16x8*)&sA[(mi * 16 + lr) * 32 + lq * 8];
#pragma unroll
        for (int ni = 0; ni < 4; ++ni)
            bv[ni] = *(const bf16x8*)&sB[(w * 64 + ni * 16 + lr) * 32 + lq * 8];
#pragma unroll
        for (int mi = 0; mi < 4; ++mi)
#pragma unroll
            for (int ni = 0; ni < 4; ++ni)
                acc[mi][ni] = __builtin_amdgcn_mfma_f32_16x16x32_bf16(af[mi], bv[ni], acc[mi][ni], 0, 0, 0);
        __syncthreads();
    }

    // epilogue: wave owns 64 rows (j) x 64 cols
    int cbase = half * 256 + w * 64;
    const float* nmb = nm_in + (size_t)b * 32768;
    const int* mrow = mask + g * 64;
    float dv = denom[g];

    float nmraw[4], nmi4[4];
#pragma unroll
    for (int ni = 0; ni < 4; ++ni) {
        int c = cbase + ni * 16 + lr;
        nmraw[ni] = nm_in[(size_t)g * 512 + c];
        nmi4[ni] = nmraw[ni] + eBt[c];
    }
    float aggv[4] = {};
#pragma unroll
    for (int mi = 0; mi < 4; ++mi) {
#pragma unroll
        for (int r = 0; r < 4; ++r) {
            int j = mi * 16 + lq * 4 + r;
            float mf = (float)mrow[j];
            const float* nrow = nmb + (size_t)j * 512;
            size_t erow = ((size_t)(g * 64 + j)) * 512;
#pragma unroll
            for (int ni = 0; ni < 4; ++ni) {
                int c = cbase + ni * 16 + lr;
                float nmj = nrow[c];
                float es = lrelu(acc[mi][ni][r] + nmi4[ni] + nmj);
                if (write_es) es_dst[erow + c] = __float2bfloat16(es);
                aggv[ni] += es * nmj * mf;
            }
        }
    }
#pragma unroll
    for (int ni = 0; ni < 4; ++ni) {
        float v = aggv[ni];
        v += __shfl_xor(v, 16, 64);
        v += __shfl_xor(v, 32, 64);
        if (lq == 0) {
            int c = cbase + ni * 16 + lr;
            size_t idx = (size_t)g * 512 + c;
            float nf = (nmraw[ni] + v) / dv;
            float ns = nodef[idx] + lrelu(nf);
            nodef[idx] = ns;
            nodeb[idx] = __float2bfloat16(ns);
        }
    }
}

// ---------------------------------------------------------------------------
__global__ __launch_bounds__(256) void out_kernel(
    const float* __restrict__ nodef, float* __restrict__ out)
{
    size_t ch = (size_t)blockIdx.x * 256 + threadIdx.x;  // 8,388,608 float4
    int c4 = (int)(ch & 255);
    size_t r = ch >> 8;
    int b = (int)(r >> 12);
    int i = (int)((r >> 6) & 63);
    int j = (int)(r & 63);
    int c = c4 * 4;
    const float* src = (c < 512) ? (nodef + ((size_t)(b * 64 + i)) * 512 + c)
                                 : (nodef + ((size_t)(b * 64 + j)) * 512 + (c - 512));
    ((float4*)out)[ch] = *(const float4*)src;
}

// ---------------------------------------------------------------------------
extern "C" void kernel_launch(void* const* d_in, const int* in_sizes, int n_in,
                              void* d_out, int out_size, void* d_ws, size_t ws_size,
                              hipStream_t stream) {
    const float* roi  = (const float*)d_in[0];
    const float* img  = (const float*)d_in[1];
    const float* nW   = (const float*)d_in[2];
    const float* nB   = (const float*)d_in[3];
    const float* eW   = (const float*)d_in[4];
    const float* eB   = (const float*)d_in[5];
    const int*   mask = (const int*)d_in[6];

    char* ob = (char*)d_out;
    __hip_bfloat16* es0   = (__hip_bfloat16*)(ob);                 // 33.55 MB
    __hip_bfloat16* es1   = (__hip_bfloat16*)(ob + 33554432);      // 33.55 MB
    __hip_bfloat16* eWb   = (__hip_bfloat16*)(ob + 67108864);      // 2.62 MB
    __hip_bfloat16* nWb   = (__hip_bfloat16*)(ob + 69730304);      // 2.62 MB
    __hip_bfloat16* nodeb = (__hip_bfloat16*)(ob + 72351744);      // 0.52 MB
    float*          nmA   = (float*)(ob + 72876032);               // 1.05 MB
    float*          nmB   = (float*)(ob + 73924608);               // 1.05 MB
    float*          em0   = (float*)(ob + 74973184);               // 16 KB
    float*       edge_init= (float*)(ob + 74989568);               // 16 KB

    char* ws = (char*)d_ws;  // read by out_kernel while d_out is rewritten
    float* nodef = (float*)(ws);                 // 1 MB
    float* denom = (float*)(ws + 1048576);       // 2 KB
    float* outp  = (float*)d_out;

    prep_kernel<<<3842, 256, 0, stream>>>(roi, img, nW, eW, mask,
                                          nWb, eWb, nodef, nodeb, edge_init, denom);
    nm0em0_kernel<<<192, 256, 0, stream>>>(nodeb, nWb, nB, edge_init, eW, eB,
                                           nmA, em0);
    // t=0: consumes nmA; fused GEMV produces nm for layer 1 into nmB
    edge_rank1<<<512, 256, 0, stream>>>(nmA, em0, mask, es0, denom, nodef,
                                        nodeb, nWb + 262144, nB + 512, nmB);
    // t=1..4
    for (int t = 1; t < 5; ++t) {
        const __hip_bfloat16* src = (t & 1) ? es0 : es1;
        __hip_bfloat16* dst       = (t & 1) ? es1 : es0;
        float* nin  = (t & 1) ? nmB : nmA;
        edge_kernel<<<1024, 256, 0, stream>>>(src, eWb + (size_t)t * 262144,
                                              eB + t * 512, nin, mask, dst,
                                              denom, nodef, nodeb,
                                              (t < 4) ? 1 : 0);
        if (t < 4) {
            float* nout = (t & 1) ? nmA : nmB;
            nm_gemm<<<dim3(8, 8), 256, 0, stream>>>(nodeb,
                                                    nWb + (size_t)(t + 1) * 262144,
                                                    nB + (t + 1) * 512, nout);
        }
    }
    out_kernel<<<32768, 256, 0, stream>>>(nodef, outp);
}